// Round 22
// baseline (198.982 us; speedup 1.0000x reference)
//
#include <hip/hip_runtime.h>
#include <hip/hip_fp16.h>
#include <math.h>

#define N_TOK 4096
#define EMB   768
#define NH    12
#define HD    64
#define FFN   3072
#define LN_EPS 1e-5f

typedef __attribute__((ext_vector_type(8))) _Float16 h8v;  // 8 f16 = 4 VGPR (MFMA A/B frag)
typedef __attribute__((ext_vector_type(8))) short    s8v;  // raw 16B copy
typedef __attribute__((ext_vector_type(4))) float    f32x4;

typedef __attribute__((address_space(3))) ushort       lus;   // LDS pointee
typedef __attribute__((address_space(1))) const ushort gus;   // global pointee

__device__ __forceinline__ ushort f2h(float f) {
    return __half_as_ushort(__float2half(f));   // v_cvt_f16_f32, RTE
}
__device__ __forceinline__ float h2f(ushort u) {
    return __half2float(__ushort_as_half(u));
}

// ---------------------------------------------------------------------------
// prep: ONE kernel for x->f16 convert + all 6 weight transpose-converts.
// ---------------------------------------------------------------------------
__global__ __launch_bounds__(256) void prep_kernel(
    const float* __restrict__ x, ushort* __restrict__ xs,
    const float* __restrict__ Wq, const float* __restrict__ Wk,
    const float* __restrict__ Wv, const float* __restrict__ Wo,
    const float* __restrict__ W1, const float* __restrict__ W2,
    ushort* __restrict__ WqT, ushort* __restrict__ WkT,
    ushort* __restrict__ WvT, ushort* __restrict__ WoT,
    ushort* __restrict__ W1T, ushort* __restrict__ W2T)
{
    __shared__ float tile[64][65];
    const int bx = blockIdx.x;
    if (bx < 3072) {
        const int i = bx * 256 + threadIdx.x;
        float4 v = ((const float4*)x)[i];
        ushort4 H;
        H.x = f2h(v.x); H.y = f2h(v.y); H.z = f2h(v.z); H.w = f2h(v.w);
        *(ushort4*)&xs[(size_t)i * 4] = H;
        return;
    }
    int wid = bx - 3072;
    const float* W; ushort* T; int K, N, txi, tyi;
    if (wid < 576) {
        const int w = wid / 144, r = wid % 144;
        W = (w == 0) ? Wq : (w == 1) ? Wk : (w == 2) ? Wv : Wo;
        T = (w == 0) ? WqT : (w == 1) ? WkT : (w == 2) ? WvT : WoT;
        K = EMB; N = EMB; txi = r % 12; tyi = r / 12;
    } else if (wid < 1152) {
        const int r = wid - 576;
        W = W1; T = W1T; K = EMB; N = FFN; txi = r % 48; tyi = r / 48;
    } else {
        const int r = wid - 1152;
        W = W2; T = W2T; K = FFN; N = EMB; txi = r % 12; tyi = r / 12;
    }
    const int k0 = tyi * 64, n0 = txi * 64;
    const int tx = threadIdx.x & 15, ty = threadIdx.x >> 4;
    #pragma unroll
    for (int rr = 0; rr < 64; rr += 16) {
        float4 v = *(const float4*)&W[(size_t)(k0 + rr + ty) * N + n0 + tx * 4];
        tile[rr + ty][tx * 4 + 0] = v.x; tile[rr + ty][tx * 4 + 1] = v.y;
        tile[rr + ty][tx * 4 + 2] = v.z; tile[rr + ty][tx * 4 + 3] = v.w;
    }
    __syncthreads();
    #pragma unroll
    for (int rr = 0; rr < 64; rr += 16) {
        const int n = rr + ty;
        ushort4 H;
        H.x = f2h(tile[tx * 4 + 0][n]); H.y = f2h(tile[tx * 4 + 1][n]);
        H.z = f2h(tile[tx * 4 + 2][n]); H.w = f2h(tile[tx * 4 + 3][n]);
        *(ushort4*)&T[(size_t)(n0 + n) * K + k0 + tx * 4] = H;
    }
}

// ---------------------------------------------------------------------------
// Per-head-slab transpose: Vp flat [12][4096][64] f16 -> Vt [12][64][4096].
// ---------------------------------------------------------------------------
__global__ __launch_bounds__(256) void vtrans_kernel(
    const ushort* __restrict__ Vp, ushort* __restrict__ Vt)
{
    __shared__ ushort tile[64 * 72];
    const int hh = blockIdx.y, k0 = blockIdx.x * 64;
    const ushort* Vh = Vp + (size_t)hh * N_TOK * HD;
    const int t = threadIdx.x;
    const int r = t >> 2, cb = (t & 3) * 16;
    #pragma unroll
    for (int u = 0; u < 2; ++u) {
        s8v v = *(const s8v*)&Vh[(size_t)(k0 + r) * HD + cb + u * 8];
        *(s8v*)&tile[r * 72 + cb + u * 8] = v;
    }
    __syncthreads();
    const int d = t >> 2, kb = (t & 3) * 16;
    ushort o[16];
    #pragma unroll
    for (int i = 0; i < 16; ++i) o[i] = tile[(kb + i) * 72 + d];
    size_t ob = (size_t)hh * N_TOK * HD + (size_t)d * N_TOK + k0 + kb;
    *(s8v*)&Vt[ob]     = *(s8v*)&o[0];
    *(s8v*)&Vt[ob + 8] = *(s8v*)&o[8];
}

// ---------------------------------------------------------------------------
// f16 MFMA GEMM, global_load_lds staging. Tile BM x BN = (MR*32) x (NRF*32),
// BK=64, 4 waves as 2x2. Kloop = K-loop bound (split-K when < K); K remains
// the row stride of A and Bt. OUTMODE 0 = f32 C; 1 = f16 plane(s).
// TRIPLE: fused QKV plane split.
// ---------------------------------------------------------------------------
template<int MR, int NRF, bool RELU, bool BIAS, int OUTMODE, bool TRIPLE>
__global__ __launch_bounds__(256) void gemm_mfma(
    const ushort* __restrict__ A, const ushort* __restrict__ Bt,
    const float* __restrict__ bias,
    float* __restrict__ C, ushort* __restrict__ Ch,
    ushort* __restrict__ Ch1, ushort* __restrict__ Ch2,
    int M, int K, int N, int Kloop)
{
    constexpr int BM = MR * 32, BN = NRF * 32, BK = 64;
    __shared__ __align__(16) ushort As[BM * BK];   // linear, chunk-swizzled
    __shared__ __align__(16) ushort Bs[BN * BK];

    const int t = threadIdx.x;
    const int wave = t >> 6, lane = t & 63;
    const int wr = wave >> 1, wc = wave & 1;
    const int row0 = blockIdx.y * BM, col0 = blockIdx.x * BN;
    const int am = lane & 15;
    const int sg = lane >> 4;          // k sub-group 0..3

    f32x4 acc[MR][NRF] = {};

    for (int k0 = 0; k0 < Kloop; k0 += BK) {
        __syncthreads();
        #pragma unroll
        for (int it = 0; it < MR; ++it) {
            const int r  = it * 32 + wave * 8 + (lane >> 3);
            const int cc = (lane & 7) ^ (r & 7);
            __builtin_amdgcn_global_load_lds(
                (gus*)&A[(size_t)(row0 + r) * K + k0 + cc * 8],
                (lus*)&As[it * 2048 + wave * 512], 16, 0, 0);
        }
        #pragma unroll
        for (int it = 0; it < NRF; ++it) {
            const int r  = it * 32 + wave * 8 + (lane >> 3);
            const int cc = (lane & 7) ^ (r & 7);
            __builtin_amdgcn_global_load_lds(
                (gus*)&Bt[(size_t)(col0 + r) * K + k0 + cc * 8],
                (lus*)&Bs[it * 2048 + wave * 512], 16, 0, 0);
        }
        __syncthreads();

        h8v af[MR][2], bf[NRF][2];
        #pragma unroll
        for (int i = 0; i < MR; ++i) {
            const int r = wr * (MR * 16) + i * 16 + am;
            #pragma unroll
            for (int s = 0; s < 2; ++s) {
                const int c = (s * 4 + sg) ^ (r & 7);
                af[i][s] = *(const h8v*)&As[r * 64 + c * 8];
            }
        }
        #pragma unroll
        for (int j = 0; j < NRF; ++j) {
            const int r = wc * (NRF * 16) + j * 16 + am;
            #pragma unroll
            for (int s = 0; s < 2; ++s) {
                const int c = (s * 4 + sg) ^ (r & 7);
                bf[j][s] = *(const h8v*)&Bs[r * 64 + c * 8];
            }
        }
        #pragma unroll
        for (int s = 0; s < 2; ++s)
            #pragma unroll
            for (int i = 0; i < MR; ++i)
                #pragma unroll
                for (int j = 0; j < NRF; ++j)
                    acc[i][j] = __builtin_amdgcn_mfma_f32_16x16x32_f16(af[i][s], bf[j][s], acc[i][j], 0, 0, 0);
    }

    ushort* hbase = Ch;
    int coff = 0, Nout = N;
    if (TRIPLE) {
        const int pl = col0 / EMB;
        hbase = (pl == 0) ? Ch : ((pl == 1) ? Ch1 : Ch2);
        coff = pl * EMB;
        Nout = EMB;
    }
    #pragma unroll
    for (int j = 0; j < NRF; ++j) {
        const int col = col0 + wc * (NRF * 16) + j * 16 + am;
        const float bv = BIAS ? bias[col] : 0.0f;
        #pragma unroll
        for (int i = 0; i < MR; ++i) {
            #pragma unroll
            for (int q = 0; q < 4; ++q) {
                const int row = row0 + wr * (MR * 16) + i * 16 + sg * 4 + q;
                float v = acc[i][j][q] + bv;
                if (RELU) v = fmaxf(v, 0.0f);
                if (OUTMODE == 0) C[(size_t)row * N + col] = v;
                else              hbase[(size_t)row * Nout + (col - coff)] = f2h(v);
            }
        }
    }
}

// ---------------------------------------------------------------------------
// Split-K f16 MFMA causal flash attention chunk (validated round-19/21, CH=8).
// ---------------------------------------------------------------------------
#define SWZ(row, blk) (((row) << 6) + ((((blk) ^ ((row) & 7))) << 3))

__global__ __launch_bounds__(256) void attn_chunk(
    const ushort* __restrict__ Qp, const ushort* __restrict__ Kp,
    const ushort* __restrict__ Vt,
    ushort* __restrict__ pctx, float* __restrict__ pml,
    ushort* __restrict__ co)
{
    __shared__ __align__(16) ushort smem[20480];   // 40 KB
    float* C64 = (float*)smem;                     // epilogue overlay

    const int hh = blockIdx.y;
    const int bxr = 287 - (int)blockIdx.x;
    int g = 0;
    #pragma unroll
    for (int gg = 1; gg < 8; ++gg)
        if (bxr >= 4 * gg * (gg + 1)) g = gg;
    const int j = bxr - 4 * g * (g + 1);
    const int qt = g * 8 + j / (g + 1);
    const int c  = j % (g + 1);

    const int q0 = qt * 64;
    const int ktlo = c * 8;
    const int kthi = min(ktlo + 8, qt + 1);

    const ushort* Qhh = Qp + (size_t)hh * N_TOK * HD;
    const ushort* Khh = Kp + (size_t)hh * N_TOK * HD;
    const ushort* Vth = Vt + (size_t)hh * N_TOK * HD;   // [64][4096]

    const int t    = threadIdx.x;
    const int wq   = t >> 6;
    const int lane = t & 63;
    const int col  = lane & 15;
    const int grp  = lane >> 4;
    const int qg   = q0 + wq * 16 + col;

    const int r  = t >> 2;            // staged row (k for K, d for VT)
    const int cb = (t & 3) * 16;      // 16-elem chunk base

    // ---- stage Q once (into Ks buf0 region) ----
    #pragma unroll
    for (int u = 0; u < 2; ++u) {
        s8v qv = *(const s8v*)&Qhh[(size_t)(q0 + r) * HD + cb + u * 8];
        *(s8v*)&smem[SWZ(r, (cb >> 3) + u)] = qv;
    }
    __syncthreads();
    h8v bq[2];
    #pragma unroll
    for (int s = 0; s < 2; ++s) {
        bq[s] = *(const h8v*)&smem[SWZ(wq * 16 + col, s * 4 + grp)];
        bq[s] = bq[s] * (_Float16)0.1803368801f;   // log2(e)/8
    }
    __syncthreads();

    h8v ones1;
    #pragma unroll
    for (int e = 0; e < 8; ++e) ones1[e] = (_Float16)1.0f;

    // ---- prefetch first tile ----
    s8v kv[2], vv[2];
    #pragma unroll
    for (int u = 0; u < 2; ++u) {
        kv[u] = *(const s8v*)&Khh[((size_t)ktlo * 64 + r) * HD + cb + u * 8];
        vv[u] = *(const s8v*)&Vth[(size_t)r * N_TOK + ktlo * 64 + cb + u * 8];
    }

    f32x4 lacc = {};
    f32x4 ctxT[4] = {};

    for (int kt = ktlo; kt < kthi; ++kt) {
        const int b = (kt - ktlo) & 1;
        ushort* Ks = smem + b * 4096;
        ushort* VT = smem + 8192 + b * 4096;
        ushort* Pw = smem + 16384 + wq * 1024;

        #pragma unroll
        for (int u = 0; u < 2; ++u) {
            *(s8v*)&Ks[SWZ(r, (cb >> 3) + u)] = kv[u];
            *(s8v*)&VT[SWZ(r, (cb >> 3) + u)] = vv[u];
        }
        __syncthreads();

        if (kt + 1 < kthi) {
            #pragma unroll
            for (int u = 0; u < 2; ++u) {
                kv[u] = *(const s8v*)&Khh[((size_t)(kt + 1) * 64 + r) * HD + cb + u * 8];
                vv[u] = *(const s8v*)&Vth[(size_t)r * N_TOK + (kt + 1) * 64 + cb + u * 8];
            }
        }

        f32x4 sacc[4] = {};
        #pragma unroll
        for (int j2 = 0; j2 < 4; ++j2)
            #pragma unroll
            for (int s = 0; s < 2; ++s) {
                h8v ah = *(const h8v*)&Ks[SWZ(j2 * 16 + col, s * 4 + grp)];
                sacc[j2] = __builtin_amdgcn_mfma_f32_16x16x32_f16(ah, bq[s], sacc[j2], 0, 0, 0);
            }

        float p_[4][4];
        if (kt == qt) {
            #pragma unroll
            for (int j2 = 0; j2 < 4; ++j2)
                #pragma unroll
                for (int rr = 0; rr < 4; ++rr) {
                    const int kgi = kt * 64 + j2 * 16 + grp * 4 + rr;
                    p_[j2][rr] = (kgi <= qg) ? exp2f(sacc[j2][rr]) : 0.0f;
                }
        } else {
            #pragma unroll
            for (int j2 = 0; j2 < 4; ++j2)
                #pragma unroll
                for (int rr = 0; rr < 4; ++rr)
                    p_[j2][rr] = exp2f(sacc[j2][rr]);
        }

        #pragma unroll
        for (int j2 = 0; j2 < 4; ++j2) {
            auto plo = __builtin_amdgcn_cvt_pkrtz(p_[j2][0], p_[j2][1]);
            auto phi = __builtin_amdgcn_cvt_pkrtz(p_[j2][2], p_[j2][3]);
            uint2 u;
            u.x = *(uint*)&plo; u.y = *(uint*)&phi;
            *(uint2*)&Pw[SWZ(col, j2 * 2 + (grp >> 1)) + (grp & 1) * 4] = u;
        }

        #pragma unroll
        for (int s = 0; s < 2; ++s) {
            h8v bp = *(const h8v*)&Pw[SWZ(col, s * 4 + grp)];
            lacc = __builtin_amdgcn_mfma_f32_16x16x32_f16(ones1, bp, lacc, 0, 0, 0);
            #pragma unroll
            for (int mt = 0; mt < 4; ++mt) {
                h8v av = *(const h8v*)&VT[SWZ(mt * 16 + col, s * 4 + grp)];
                ctxT[mt] = __builtin_amdgcn_mfma_f32_16x16x32_f16(av, bp, ctxT[mt], 0, 0, 0);
            }
        }
    }

    const float inv = 1.0f / lacc[0];

    if (qt < 8) {
        __syncthreads();
        #pragma unroll
        for (int mt = 0; mt < 4; ++mt)
            #pragma unroll
            for (int rr = 0; rr < 4; ++rr)
                C64[(wq * 16 + col) * 68 + mt * 16 + grp * 4 + rr] = ctxT[mt][rr] * inv;
        __syncthreads();
        #pragma unroll
        for (int pass = 0; pass < 4; ++pass) {
            const int row = pass * 16 + (t >> 4);
            const int cidx = (t & 15) * 4;
            float4 v = *(float4*)&C64[row * 68 + cidx];
            ushort4 H;
            H.x = f2h(v.x); H.y = f2h(v.y); H.z = f2h(v.z); H.w = f2h(v.w);
            *(ushort4*)&co[(size_t)(q0 + row) * EMB + hh * HD + cidx] = H;
        }
        return;
    }

    const int p = (hh * 64 + qt) * 8 + c;
    if (grp == 0) pml[(size_t)p * 128 + wq * 16 + col] = lacc[0];
    #pragma unroll
    for (int mt = 0; mt < 4; ++mt)
        #pragma unroll
        for (int rr = 0; rr < 4; ++rr) {
            const int d = mt * 16 + grp * 4 + rr;
            pctx[(size_t)p * 4096 + d * 64 + wq * 16 + col] = f2h(ctxT[mt][rr] * inv);
        }
}

// ---------------------------------------------------------------------------
// Combine for multi-chunk qtiles (qt >= 8): l-weighted average.
// ---------------------------------------------------------------------------
__global__ __launch_bounds__(256) void attn_combine(
    const ushort* __restrict__ pctx, const float* __restrict__ pml,
    ushort* __restrict__ co)
{
    __shared__ float ml[8 * 64];
    __shared__ ushort Ct[64 * 68];
    const int qt = 8 + blockIdx.x, hh = blockIdx.y;
    const int nch = qt / 8 + 1;
    const int base = (hh * 64 + qt) * 8;
    const int t = threadIdx.x;

    for (int idx = t; idx < nch * 64; idx += 256)
        ml[idx] = pml[(size_t)(base + idx / 64) * 128 + (idx & 63)];
    __syncthreads();

    const int lane = t & 63, w = t >> 6;
    float lsum = 0.0f;
    float accs[16] = {};
    for (int c = 0; c < nch; ++c) {
        const float wgt = ml[c * 64 + lane];
        lsum += wgt;
        const ushort* pc = pctx + (size_t)(base + c) * 4096 + w * 16 * 64 + lane;
        #pragma unroll
        for (int dd = 0; dd < 16; ++dd)
            accs[dd] += wgt * h2f(pc[dd * 64]);
    }
    const float inv = 1.0f / lsum;
    #pragma unroll
    for (int dd = 0; dd < 16; ++dd)
        Ct[lane * 68 + w * 16 + dd] = f2h(accs[dd] * inv);
    __syncthreads();

    const int q0 = qt * 64;
    #pragma unroll
    for (int pass = 0; pass < 4; ++pass) {
        const int row = pass * 16 + (t >> 4);
        const int cidx = (t & 15) * 4;
        ushort4 H = *(ushort4*)&Ct[row * 68 + cidx];
        *(ushort4*)&co[(size_t)(q0 + row) * EMB + hh * HD + cidx] = H;
    }
}

// ---------------------------------------------------------------------------
// Fused residual + LayerNorm. THREE: x = a + b + c2 + bias2 (split-K FFN2
// reduction folded in). Optionally emits f16 plane.
// ---------------------------------------------------------------------------
template<bool EMIT_H, bool THREE>
__global__ __launch_bounds__(256) void ln_kernel(
    const float* __restrict__ a, const float* __restrict__ b,
    const float* __restrict__ c2, const float* __restrict__ bias2,
    const float* __restrict__ g, const float* __restrict__ beta,
    float* __restrict__ out, ushort* __restrict__ oh)
{
    const int row = blockIdx.x;
    const int t = threadIdx.x;
    float v[3];
    float sum = 0.f, sumsq = 0.f;
    #pragma unroll
    for (int i = 0; i < 3; ++i) {
        const int c = t + i * 256;
        float x = a[(size_t)row * EMB + c] + b[(size_t)row * EMB + c];
        if (THREE) x += c2[(size_t)row * EMB + c] + bias2[c];
        v[i] = x; sum += x; sumsq += x * x;
    }
    #pragma unroll
    for (int off = 32; off >= 1; off >>= 1) {
        sum   += __shfl_xor(sum, off);
        sumsq += __shfl_xor(sumsq, off);
    }
    __shared__ float ws[8];
    const int wave = t >> 6, lane = t & 63;
    if (lane == 0) { ws[wave] = sum; ws[4 + wave] = sumsq; }
    __syncthreads();
    sum   = ws[0] + ws[1] + ws[2] + ws[3];
    sumsq = ws[4] + ws[5] + ws[6] + ws[7];
    const float mu  = sum * (1.0f / EMB);
    const float var = sumsq * (1.0f / EMB) - mu * mu;
    const float rs  = rsqrtf(var + LN_EPS);
    #pragma unroll
    for (int i = 0; i < 3; ++i) {
        const int c = t + i * 256;
        float x = a[(size_t)row * EMB + c] + b[(size_t)row * EMB + c];
        if (THREE) x += c2[(size_t)row * EMB + c] + bias2[c];
        const float y = (x - mu) * rs * g[c] + beta[c];
        const size_t o = (size_t)row * EMB + c;
        out[o] = y;
        if (EMIT_H) oh[o] = f2h(y);
    }
}

// ---------------------------------------------------------------------------
extern "C" void kernel_launch(void* const* d_in, const int* in_sizes, int n_in,
                              void* d_out, int out_size, void* d_ws, size_t ws_size,
                              hipStream_t stream)
{
    (void)in_sizes; (void)n_in; (void)out_size; (void)ws_size;
    const float* x     = (const float*)d_in[0];
    const float* Wq    = (const float*)d_in[1];
    const float* Wk    = (const float*)d_in[2];
    const float* Wv    = (const float*)d_in[3];
    const float* Wo    = (const float*)d_in[4];
    const float* W1    = (const float*)d_in[5];
    const float* b1    = (const float*)d_in[6];
    const float* W2    = (const float*)d_in[7];
    const float* b2    = (const float*)d_in[8];
    const float* g1    = (const float*)d_in[9];
    const float* beta1 = (const float*)d_in[10];
    const float* g2    = (const float*)d_in[11];
    const float* beta2 = (const float*)d_in[12];
    float* out = (float*)d_out;

    const size_t NE = (size_t)N_TOK * EMB;      // 3,145,728 elems
    ushort* wsu = (ushort*)d_ws;
    ushort* Qp  = wsu;
    ushort* Kp  = wsu + NE;
    ushort* Vp  = wsu + 2 * NE;
    ushort* xs  = wsu + 3 * NE;
    ushort* cs  = wsu + 3 * NE;
    float*  tmp  = (float*)(wsu + 4 * NE);
    float*  tmp2a = tmp;
    float*  h1   = (float*)(wsu + 6 * NE);
    ushort* h1s  = wsu + 8 * NE;
    ushort* ff1  = wsu;

    const size_t WEE = (size_t)EMB * EMB;
    const size_t WEF = (size_t)EMB * FFN;
    ushort* WqT = wsu + 9 * NE;
    ushort* WkT = WqT + WEE;
    ushort* WvT = WkT + WEE;
    ushort* WoT = WvT + WEE;
    ushort* W1T = WoT + WEE;
    ushort* W2T = W1T + WEF;
    ushort* Vt   = W2T + WEF;                       // NE ushorts
    ushort* pctx = Vt + NE;                         // 12*64*8*4096 ushorts (~50MB)
    float*  pml  = (float*)(pctx + (size_t)12 * 64 * 8 * 4096);  // 12*64*8*128 f32
    float*  tmp2b = (float*)pctx;                   // pctx dead after combine

    const dim3 blk(256);

    // ---- phase 1: all conversions in one launch ----
    prep_kernel<<<dim3(4800), blk, 0, stream>>>(
        x, xs, Wq, Wk, Wv, Wo, W1, W2, WqT, WkT, WvT, WoT, W1T, W2T);

    // ---- phase 2: fused QKV projection, BN=128 tile ----
    gemm_mfma<4, 4, false, false, 1, true><<<dim3(3 * EMB / 128, N_TOK / 128), blk, 0, stream>>>(
        xs, WqT, nullptr, nullptr, Qp, Kp, Vp, N_TOK, EMB, 3 * EMB, EMB);

    // ---- phase 2b: V per-head-slab transpose ----
    vtrans_kernel<<<dim3(N_TOK / 64, NH), blk, 0, stream>>>(Vp, Vt);

    // ---- phase 3: split-K causal attention (CH=8, 3456 blocks) + combine ----
    attn_chunk<<<dim3(288, NH), blk, 0, stream>>>(Qp, Kp, Vt, pctx, pml, cs);
    attn_combine<<<dim3(56, NH), blk, 0, stream>>>(pctx, pml, cs);

    // ---- phase 4: output projection (BN=64 path) ----
    gemm_mfma<2, 2, false, false, 0, false><<<dim3(EMB / 64, N_TOK / 64), blk, 0, stream>>>(
        cs, WoT, nullptr, tmp, nullptr, nullptr, nullptr, N_TOK, EMB, EMB, EMB);

    // ---- phase 5: h1 = LN(x + attn_out) + f16 plane ----
    ln_kernel<true, false><<<dim3(N_TOK), blk, 0, stream>>>(
        x, tmp, nullptr, nullptr, g1, beta1, h1, h1s);

    // ---- phase 6: ff1 = relu(h1 @ W1 + b1), BN=128 tile ----
    gemm_mfma<4, 4, true, true, 1, false><<<dim3(FFN / 128, N_TOK / 128), blk, 0, stream>>>(
        h1s, W1T, b1, nullptr, ff1, nullptr, nullptr, N_TOK, EMB, FFN, EMB);

    // ---- phase 7: ff2 = ff1 @ W2 (split-K x2; bias + reduce folded in LN2) ----
    gemm_mfma<2, 2, false, false, 0, false><<<dim3(EMB / 64, N_TOK / 64), blk, 0, stream>>>(
        ff1, W2T, nullptr, tmp2a, nullptr, nullptr, nullptr, N_TOK, FFN, EMB, FFN / 2);
    gemm_mfma<2, 2, false, false, 0, false><<<dim3(EMB / 64, N_TOK / 64), blk, 0, stream>>>(
        ff1 + FFN / 2, W2T + FFN / 2, nullptr, tmp2b, nullptr, nullptr, nullptr, N_TOK, FFN, EMB, FFN / 2);

    // ---- phase 8: out = LN(h1 + ff2a + ff2b + b2) ----
    ln_kernel<false, true><<<dim3(N_TOK), blk, 0, stream>>>(
        h1, tmp2a, tmp2b, b2, g2, beta2, out, nullptr);
}

// Round 23
// 192.340 us; speedup vs baseline: 1.0345x; 1.0345x over previous
//
#include <hip/hip_runtime.h>
#include <hip/hip_fp16.h>
#include <math.h>

#define N_TOK 4096
#define EMB   768
#define NH    12
#define HD    64
#define FFN   3072
#define LN_EPS 1e-5f

typedef __attribute__((ext_vector_type(8))) _Float16 h8v;  // 8 f16 = 4 VGPR (MFMA A/B frag)
typedef __attribute__((ext_vector_type(8))) short    s8v;  // raw 16B copy
typedef __attribute__((ext_vector_type(4))) float    f32x4;

typedef __attribute__((address_space(3))) ushort       lus;   // LDS pointee
typedef __attribute__((address_space(1))) const ushort gus;   // global pointee

__device__ __forceinline__ ushort f2h(float f) {
    return __half_as_ushort(__float2half(f));   // v_cvt_f16_f32, RTE
}
__device__ __forceinline__ float h2f(ushort u) {
    return __half2float(__ushort_as_half(u));
}

// ---------------------------------------------------------------------------
// prep: ONE kernel for x->f16 convert + all 6 weight transpose-converts.
// ---------------------------------------------------------------------------
__global__ __launch_bounds__(256) void prep_kernel(
    const float* __restrict__ x, ushort* __restrict__ xs,
    const float* __restrict__ Wq, const float* __restrict__ Wk,
    const float* __restrict__ Wv, const float* __restrict__ Wo,
    const float* __restrict__ W1, const float* __restrict__ W2,
    ushort* __restrict__ WqT, ushort* __restrict__ WkT,
    ushort* __restrict__ WvT, ushort* __restrict__ WoT,
    ushort* __restrict__ W1T, ushort* __restrict__ W2T)
{
    __shared__ float tile[64][65];
    const int bx = blockIdx.x;
    if (bx < 3072) {
        const int i = bx * 256 + threadIdx.x;
        float4 v = ((const float4*)x)[i];
        ushort4 H;
        H.x = f2h(v.x); H.y = f2h(v.y); H.z = f2h(v.z); H.w = f2h(v.w);
        *(ushort4*)&xs[(size_t)i * 4] = H;
        return;
    }
    int wid = bx - 3072;
    const float* W; ushort* T; int K, N, txi, tyi;
    if (wid < 576) {
        const int w = wid / 144, r = wid % 144;
        W = (w == 0) ? Wq : (w == 1) ? Wk : (w == 2) ? Wv : Wo;
        T = (w == 0) ? WqT : (w == 1) ? WkT : (w == 2) ? WvT : WoT;
        K = EMB; N = EMB; txi = r % 12; tyi = r / 12;
    } else if (wid < 1152) {
        const int r = wid - 576;
        W = W1; T = W1T; K = EMB; N = FFN; txi = r % 48; tyi = r / 48;
    } else {
        const int r = wid - 1152;
        W = W2; T = W2T; K = FFN; N = EMB; txi = r % 12; tyi = r / 12;
    }
    const int k0 = tyi * 64, n0 = txi * 64;
    const int tx = threadIdx.x & 15, ty = threadIdx.x >> 4;
    #pragma unroll
    for (int rr = 0; rr < 64; rr += 16) {
        float4 v = *(const float4*)&W[(size_t)(k0 + rr + ty) * N + n0 + tx * 4];
        tile[rr + ty][tx * 4 + 0] = v.x; tile[rr + ty][tx * 4 + 1] = v.y;
        tile[rr + ty][tx * 4 + 2] = v.z; tile[rr + ty][tx * 4 + 3] = v.w;
    }
    __syncthreads();
    #pragma unroll
    for (int rr = 0; rr < 64; rr += 16) {
        const int n = rr + ty;
        ushort4 H;
        H.x = f2h(tile[tx * 4 + 0][n]); H.y = f2h(tile[tx * 4 + 1][n]);
        H.z = f2h(tile[tx * 4 + 2][n]); H.w = f2h(tile[tx * 4 + 3][n]);
        *(ushort4*)&T[(size_t)(n0 + n) * K + k0 + tx * 4] = H;
    }
}

// ---------------------------------------------------------------------------
// Per-head-slab transpose: Vp flat [12][4096][64] f16 -> Vt [12][64][4096].
// ---------------------------------------------------------------------------
__global__ __launch_bounds__(256) void vtrans_kernel(
    const ushort* __restrict__ Vp, ushort* __restrict__ Vt)
{
    __shared__ ushort tile[64 * 72];
    const int hh = blockIdx.y, k0 = blockIdx.x * 64;
    const ushort* Vh = Vp + (size_t)hh * N_TOK * HD;
    const int t = threadIdx.x;
    const int r = t >> 2, cb = (t & 3) * 16;
    #pragma unroll
    for (int u = 0; u < 2; ++u) {
        s8v v = *(const s8v*)&Vh[(size_t)(k0 + r) * HD + cb + u * 8];
        *(s8v*)&tile[r * 72 + cb + u * 8] = v;
    }
    __syncthreads();
    const int d = t >> 2, kb = (t & 3) * 16;
    ushort o[16];
    #pragma unroll
    for (int i = 0; i < 16; ++i) o[i] = tile[(kb + i) * 72 + d];
    size_t ob = (size_t)hh * N_TOK * HD + (size_t)d * N_TOK + k0 + kb;
    *(s8v*)&Vt[ob]     = *(s8v*)&o[0];
    *(s8v*)&Vt[ob + 8] = *(s8v*)&o[8];
}

// ---------------------------------------------------------------------------
// f16 MFMA GEMM, global_load_lds staging. Tile BM x BN = (MR*32) x (NRF*32),
// BK=64, 4 waves as 2x2 (wave tile = MR*16 x NRF*16). NRF=2 = validated
// BN=64 path; NRF=4 = BN=128 (32 MFMA/step/wave) for wide-N GEMMs.
// OUTMODE 0 = f32 C; 1 = f16 plane(s). TRIPLE: fused QKV plane split.
// ---------------------------------------------------------------------------
template<int MR, int NRF, bool RELU, bool BIAS, int OUTMODE, bool TRIPLE>
__global__ __launch_bounds__(256) void gemm_mfma(
    const ushort* __restrict__ A, const ushort* __restrict__ Bt,
    const float* __restrict__ bias,
    float* __restrict__ C, ushort* __restrict__ Ch,
    ushort* __restrict__ Ch1, ushort* __restrict__ Ch2,
    int M, int K, int N)
{
    constexpr int BM = MR * 32, BN = NRF * 32, BK = 64;
    __shared__ __align__(16) ushort As[BM * BK];   // linear, chunk-swizzled
    __shared__ __align__(16) ushort Bs[BN * BK];

    const int t = threadIdx.x;
    const int wave = t >> 6, lane = t & 63;
    const int wr = wave >> 1, wc = wave & 1;
    const int row0 = blockIdx.y * BM, col0 = blockIdx.x * BN;
    const int am = lane & 15;
    const int sg = lane >> 4;          // k sub-group 0..3

    f32x4 acc[MR][NRF] = {};

    for (int k0 = 0; k0 < K; k0 += BK) {
        __syncthreads();
        #pragma unroll
        for (int it = 0; it < MR; ++it) {
            const int r  = it * 32 + wave * 8 + (lane >> 3);
            const int cc = (lane & 7) ^ (r & 7);
            __builtin_amdgcn_global_load_lds(
                (gus*)&A[(size_t)(row0 + r) * K + k0 + cc * 8],
                (lus*)&As[it * 2048 + wave * 512], 16, 0, 0);
        }
        #pragma unroll
        for (int it = 0; it < NRF; ++it) {
            const int r  = it * 32 + wave * 8 + (lane >> 3);
            const int cc = (lane & 7) ^ (r & 7);
            __builtin_amdgcn_global_load_lds(
                (gus*)&Bt[(size_t)(col0 + r) * K + k0 + cc * 8],
                (lus*)&Bs[it * 2048 + wave * 512], 16, 0, 0);
        }
        __syncthreads();

        h8v af[MR][2], bf[NRF][2];
        #pragma unroll
        for (int i = 0; i < MR; ++i) {
            const int r = wr * (MR * 16) + i * 16 + am;
            #pragma unroll
            for (int s = 0; s < 2; ++s) {
                const int c = (s * 4 + sg) ^ (r & 7);
                af[i][s] = *(const h8v*)&As[r * 64 + c * 8];
            }
        }
        #pragma unroll
        for (int j = 0; j < NRF; ++j) {
            const int r = wc * (NRF * 16) + j * 16 + am;
            #pragma unroll
            for (int s = 0; s < 2; ++s) {
                const int c = (s * 4 + sg) ^ (r & 7);
                bf[j][s] = *(const h8v*)&Bs[r * 64 + c * 8];
            }
        }
        #pragma unroll
        for (int s = 0; s < 2; ++s)
            #pragma unroll
            for (int i = 0; i < MR; ++i)
                #pragma unroll
                for (int j = 0; j < NRF; ++j)
                    acc[i][j] = __builtin_amdgcn_mfma_f32_16x16x32_f16(af[i][s], bf[j][s], acc[i][j], 0, 0, 0);
    }

    ushort* hbase = Ch;
    int coff = 0, Nout = N;
    if (TRIPLE) {
        const int pl = col0 / EMB;
        hbase = (pl == 0) ? Ch : ((pl == 1) ? Ch1 : Ch2);
        coff = pl * EMB;
        Nout = EMB;
    }
    #pragma unroll
    for (int j = 0; j < NRF; ++j) {
        const int col = col0 + wc * (NRF * 16) + j * 16 + am;
        const float bv = BIAS ? bias[col] : 0.0f;
        #pragma unroll
        for (int i = 0; i < MR; ++i) {
            #pragma unroll
            for (int q = 0; q < 4; ++q) {
                const int row = row0 + wr * (MR * 16) + i * 16 + sg * 4 + q;
                float v = acc[i][j][q] + bv;
                if (RELU) v = fmaxf(v, 0.0f);
                if (OUTMODE == 0) C[(size_t)row * N + col] = v;
                else              hbase[(size_t)row * Nout + (col - coff)] = f2h(v);
            }
        }
    }
}

// ---------------------------------------------------------------------------
// Split-K f16 MFMA causal flash attention chunk (validated round-19/21, CH=8).
// Reg-prefetch staging. Max-free softmax in log2 domain (no clamp); row-sum
// l on the MFMA pipe via ones-A. 40 KB LDS, 4 blocks/CU, one barrier/tile.
// ---------------------------------------------------------------------------
#define SWZ(row, blk) (((row) << 6) + ((((blk) ^ ((row) & 7))) << 3))

__global__ __launch_bounds__(256) void attn_chunk(
    const ushort* __restrict__ Qp, const ushort* __restrict__ Kp,
    const ushort* __restrict__ Vt,
    ushort* __restrict__ pctx, float* __restrict__ pml,
    ushort* __restrict__ co)
{
    __shared__ __align__(16) ushort smem[20480];   // 40 KB
    float* C64 = (float*)smem;                     // epilogue overlay

    const int hh = blockIdx.y;
    const int bxr = 287 - (int)blockIdx.x;
    int g = 0;
    #pragma unroll
    for (int gg = 1; gg < 8; ++gg)
        if (bxr >= 4 * gg * (gg + 1)) g = gg;
    const int j = bxr - 4 * g * (g + 1);
    const int qt = g * 8 + j / (g + 1);
    const int c  = j % (g + 1);

    const int q0 = qt * 64;
    const int ktlo = c * 8;
    const int kthi = min(ktlo + 8, qt + 1);

    const ushort* Qhh = Qp + (size_t)hh * N_TOK * HD;
    const ushort* Khh = Kp + (size_t)hh * N_TOK * HD;
    const ushort* Vth = Vt + (size_t)hh * N_TOK * HD;   // [64][4096]

    const int t    = threadIdx.x;
    const int wq   = t >> 6;
    const int lane = t & 63;
    const int col  = lane & 15;
    const int grp  = lane >> 4;
    const int qg   = q0 + wq * 16 + col;

    const int r  = t >> 2;            // staged row (k for K, d for VT)
    const int cb = (t & 3) * 16;      // 16-elem chunk base

    // ---- stage Q once (into Ks buf0 region) ----
    #pragma unroll
    for (int u = 0; u < 2; ++u) {
        s8v qv = *(const s8v*)&Qhh[(size_t)(q0 + r) * HD + cb + u * 8];
        *(s8v*)&smem[SWZ(r, (cb >> 3) + u)] = qv;
    }
    __syncthreads();
    h8v bq[2];
    #pragma unroll
    for (int s = 0; s < 2; ++s) {
        bq[s] = *(const h8v*)&smem[SWZ(wq * 16 + col, s * 4 + grp)];
        bq[s] = bq[s] * (_Float16)0.1803368801f;   // log2(e)/8
    }
    __syncthreads();

    h8v ones1;
    #pragma unroll
    for (int e = 0; e < 8; ++e) ones1[e] = (_Float16)1.0f;

    // ---- prefetch first tile ----
    s8v kv[2], vv[2];
    #pragma unroll
    for (int u = 0; u < 2; ++u) {
        kv[u] = *(const s8v*)&Khh[((size_t)ktlo * 64 + r) * HD + cb + u * 8];
        vv[u] = *(const s8v*)&Vth[(size_t)r * N_TOK + ktlo * 64 + cb + u * 8];
    }

    f32x4 lacc = {};
    f32x4 ctxT[4] = {};

    for (int kt = ktlo; kt < kthi; ++kt) {
        const int b = (kt - ktlo) & 1;
        ushort* Ks = smem + b * 4096;
        ushort* VT = smem + 8192 + b * 4096;
        ushort* Pw = smem + 16384 + wq * 1024;

        #pragma unroll
        for (int u = 0; u < 2; ++u) {
            *(s8v*)&Ks[SWZ(r, (cb >> 3) + u)] = kv[u];
            *(s8v*)&VT[SWZ(r, (cb >> 3) + u)] = vv[u];
        }
        __syncthreads();

        if (kt + 1 < kthi) {
            #pragma unroll
            for (int u = 0; u < 2; ++u) {
                kv[u] = *(const s8v*)&Khh[((size_t)(kt + 1) * 64 + r) * HD + cb + u * 8];
                vv[u] = *(const s8v*)&Vth[(size_t)r * N_TOK + (kt + 1) * 64 + cb + u * 8];
            }
        }

        f32x4 sacc[4] = {};
        #pragma unroll
        for (int j2 = 0; j2 < 4; ++j2)
            #pragma unroll
            for (int s = 0; s < 2; ++s) {
                h8v ah = *(const h8v*)&Ks[SWZ(j2 * 16 + col, s * 4 + grp)];
                sacc[j2] = __builtin_amdgcn_mfma_f32_16x16x32_f16(ah, bq[s], sacc[j2], 0, 0, 0);
            }

        float p_[4][4];
        if (kt == qt) {
            #pragma unroll
            for (int j2 = 0; j2 < 4; ++j2)
                #pragma unroll
                for (int rr = 0; rr < 4; ++rr) {
                    const int kgi = kt * 64 + j2 * 16 + grp * 4 + rr;
                    p_[j2][rr] = (kgi <= qg) ? exp2f(sacc[j2][rr]) : 0.0f;
                }
        } else {
            #pragma unroll
            for (int j2 = 0; j2 < 4; ++j2)
                #pragma unroll
                for (int rr = 0; rr < 4; ++rr)
                    p_[j2][rr] = exp2f(sacc[j2][rr]);
        }

        #pragma unroll
        for (int j2 = 0; j2 < 4; ++j2) {
            auto plo = __builtin_amdgcn_cvt_pkrtz(p_[j2][0], p_[j2][1]);
            auto phi = __builtin_amdgcn_cvt_pkrtz(p_[j2][2], p_[j2][3]);
            uint2 u;
            u.x = *(uint*)&plo; u.y = *(uint*)&phi;
            *(uint2*)&Pw[SWZ(col, j2 * 2 + (grp >> 1)) + (grp & 1) * 4] = u;
        }

        #pragma unroll
        for (int s = 0; s < 2; ++s) {
            h8v bp = *(const h8v*)&Pw[SWZ(col, s * 4 + grp)];
            lacc = __builtin_amdgcn_mfma_f32_16x16x32_f16(ones1, bp, lacc, 0, 0, 0);
            #pragma unroll
            for (int mt = 0; mt < 4; ++mt) {
                h8v av = *(const h8v*)&VT[SWZ(mt * 16 + col, s * 4 + grp)];
                ctxT[mt] = __builtin_amdgcn_mfma_f32_16x16x32_f16(av, bp, ctxT[mt], 0, 0, 0);
            }
        }
    }

    const float inv = 1.0f / lacc[0];

    if (qt < 8) {
        __syncthreads();
        #pragma unroll
        for (int mt = 0; mt < 4; ++mt)
            #pragma unroll
            for (int rr = 0; rr < 4; ++rr)
                C64[(wq * 16 + col) * 68 + mt * 16 + grp * 4 + rr] = ctxT[mt][rr] * inv;
        __syncthreads();
        #pragma unroll
        for (int pass = 0; pass < 4; ++pass) {
            const int row = pass * 16 + (t >> 4);
            const int cidx = (t & 15) * 4;
            float4 v = *(float4*)&C64[row * 68 + cidx];
            ushort4 H;
            H.x = f2h(v.x); H.y = f2h(v.y); H.z = f2h(v.z); H.w = f2h(v.w);
            *(ushort4*)&co[(size_t)(q0 + row) * EMB + hh * HD + cidx] = H;
        }
        return;
    }

    const int p = (hh * 64 + qt) * 8 + c;
    if (grp == 0) pml[(size_t)p * 128 + wq * 16 + col] = lacc[0];
    #pragma unroll
    for (int mt = 0; mt < 4; ++mt)
        #pragma unroll
        for (int rr = 0; rr < 4; ++rr) {
            const int d = mt * 16 + grp * 4 + rr;
            pctx[(size_t)p * 4096 + d * 64 + wq * 16 + col] = f2h(ctxT[mt][rr] * inv);
        }
}

// ---------------------------------------------------------------------------
// Combine for multi-chunk qtiles (qt >= 8): l-weighted average.
// ---------------------------------------------------------------------------
__global__ __launch_bounds__(256) void attn_combine(
    const ushort* __restrict__ pctx, const float* __restrict__ pml,
    ushort* __restrict__ co)
{
    __shared__ float ml[8 * 64];
    __shared__ ushort Ct[64 * 68];
    const int qt = 8 + blockIdx.x, hh = blockIdx.y;
    const int nch = qt / 8 + 1;
    const int base = (hh * 64 + qt) * 8;
    const int t = threadIdx.x;

    for (int idx = t; idx < nch * 64; idx += 256)
        ml[idx] = pml[(size_t)(base + idx / 64) * 128 + (idx & 63)];
    __syncthreads();

    const int lane = t & 63, w = t >> 6;
    float lsum = 0.0f;
    float accs[16] = {};
    for (int c = 0; c < nch; ++c) {
        const float wgt = ml[c * 64 + lane];
        lsum += wgt;
        const ushort* pc = pctx + (size_t)(base + c) * 4096 + w * 16 * 64 + lane;
        #pragma unroll
        for (int dd = 0; dd < 16; ++dd)
            accs[dd] += wgt * h2f(pc[dd * 64]);
    }
    const float inv = 1.0f / lsum;
    #pragma unroll
    for (int dd = 0; dd < 16; ++dd)
        Ct[lane * 68 + w * 16 + dd] = f2h(accs[dd] * inv);
    __syncthreads();

    const int q0 = qt * 64;
    #pragma unroll
    for (int pass = 0; pass < 4; ++pass) {
        const int row = pass * 16 + (t >> 4);
        const int cidx = (t & 15) * 4;
        ushort4 H = *(ushort4*)&Ct[row * 68 + cidx];
        *(ushort4*)&co[(size_t)(q0 + row) * EMB + hh * HD + cidx] = H;
    }
}

// ---------------------------------------------------------------------------
// Fused residual + LayerNorm; optionally also emits f16 plane.
// ---------------------------------------------------------------------------
template<bool EMIT_H>
__global__ __launch_bounds__(256) void ln_kernel(
    const float* __restrict__ a, const float* __restrict__ b,
    const float* __restrict__ g, const float* __restrict__ beta,
    float* __restrict__ out, ushort* __restrict__ oh)
{
    const int row = blockIdx.x;
    const int t = threadIdx.x;
    float v[3];
    float sum = 0.f, sumsq = 0.f;
    #pragma unroll
    for (int i = 0; i < 3; ++i) {
        const int c = t + i * 256;
        const float x = a[(size_t)row * EMB + c] + b[(size_t)row * EMB + c];
        v[i] = x; sum += x; sumsq += x * x;
    }
    #pragma unroll
    for (int off = 32; off >= 1; off >>= 1) {
        sum   += __shfl_xor(sum, off);
        sumsq += __shfl_xor(sumsq, off);
    }
    __shared__ float ws[8];
    const int wave = t >> 6, lane = t & 63;
    if (lane == 0) { ws[wave] = sum; ws[4 + wave] = sumsq; }
    __syncthreads();
    sum   = ws[0] + ws[1] + ws[2] + ws[3];
    sumsq = ws[4] + ws[5] + ws[6] + ws[7];
    const float mu  = sum * (1.0f / EMB);
    const float var = sumsq * (1.0f / EMB) - mu * mu;
    const float rs  = rsqrtf(var + LN_EPS);
    #pragma unroll
    for (int i = 0; i < 3; ++i) {
        const int c = t + i * 256;
        const float y = (v[i] - mu) * rs * g[c] + beta[c];
        const size_t o = (size_t)row * EMB + c;
        out[o] = y;
        if (EMIT_H) oh[o] = f2h(y);
    }
}

// ---------------------------------------------------------------------------
extern "C" void kernel_launch(void* const* d_in, const int* in_sizes, int n_in,
                              void* d_out, int out_size, void* d_ws, size_t ws_size,
                              hipStream_t stream)
{
    (void)in_sizes; (void)n_in; (void)out_size; (void)ws_size;
    const float* x     = (const float*)d_in[0];
    const float* Wq    = (const float*)d_in[1];
    const float* Wk    = (const float*)d_in[2];
    const float* Wv    = (const float*)d_in[3];
    const float* Wo    = (const float*)d_in[4];
    const float* W1    = (const float*)d_in[5];
    const float* b1    = (const float*)d_in[6];
    const float* W2    = (const float*)d_in[7];
    const float* b2    = (const float*)d_in[8];
    const float* g1    = (const float*)d_in[9];
    const float* beta1 = (const float*)d_in[10];
    const float* g2    = (const float*)d_in[11];
    const float* beta2 = (const float*)d_in[12];
    float* out = (float*)d_out;

    const size_t NE = (size_t)N_TOK * EMB;      // 3,145,728 elems
    ushort* wsu = (ushort*)d_ws;
    ushort* Qp  = wsu;
    ushort* Kp  = wsu + NE;
    ushort* Vp  = wsu + 2 * NE;
    ushort* xs  = wsu + 3 * NE;
    ushort* cs  = wsu + 3 * NE;
    float*  tmp  = (float*)(wsu + 4 * NE);
    float*  tmp2 = tmp;
    float*  h1   = (float*)(wsu + 6 * NE);
    ushort* h1s  = wsu + 8 * NE;
    ushort* ff1  = wsu;

    const size_t WEE = (size_t)EMB * EMB;
    const size_t WEF = (size_t)EMB * FFN;
    ushort* WqT = wsu + 9 * NE;
    ushort* WkT = WqT + WEE;
    ushort* WvT = WkT + WEE;
    ushort* WoT = WvT + WEE;
    ushort* W1T = WoT + WEE;
    ushort* W2T = W1T + WEF;
    ushort* Vt   = W2T + WEF;                       // NE ushorts
    ushort* pctx = Vt + NE;                         // 12*64*8*4096 ushorts (~50MB)
    float*  pml  = (float*)(pctx + (size_t)12 * 64 * 8 * 4096);  // 12*64*8*128 f32

    const dim3 blk(256);

    // ---- phase 1: all conversions in one launch ----
    prep_kernel<<<dim3(4800), blk, 0, stream>>>(
        x, xs, Wq, Wk, Wv, Wo, W1, W2, WqT, WkT, WvT, WoT, W1T, W2T);

    // ---- phase 2: fused QKV projection, BN=128 tile ----
    gemm_mfma<4, 4, false, false, 1, true><<<dim3(3 * EMB / 128, N_TOK / 128), blk, 0, stream>>>(
        xs, WqT, nullptr, nullptr, Qp, Kp, Vp, N_TOK, EMB, 3 * EMB);

    // ---- phase 2b: V per-head-slab transpose ----
    vtrans_kernel<<<dim3(N_TOK / 64, NH), blk, 0, stream>>>(Vp, Vt);

    // ---- phase 3: split-K causal attention (CH=8, 3456 blocks) + combine ----
    attn_chunk<<<dim3(288, NH), blk, 0, stream>>>(Qp, Kp, Vt, pctx, pml, cs);
    attn_combine<<<dim3(56, NH), blk, 0, stream>>>(pctx, pml, cs);

    // ---- phase 4: output projection (BN=64 path, validated) ----
    gemm_mfma<2, 2, false, false, 0, false><<<dim3(EMB / 64, N_TOK / 64), blk, 0, stream>>>(
        cs, WoT, nullptr, tmp, nullptr, nullptr, nullptr, N_TOK, EMB, EMB);

    // ---- phase 5: h1 = LN(x + attn_out) + f16 plane ----
    ln_kernel<true><<<dim3(N_TOK), blk, 0, stream>>>(x, tmp, g1, beta1, h1, h1s);

    // ---- phase 6: ff1 = relu(h1 @ W1 + b1), BN=128 tile ----
    gemm_mfma<4, 4, true, true, 1, false><<<dim3(FFN / 128, N_TOK / 128), blk, 0, stream>>>(
        h1s, W1T, b1, nullptr, ff1, nullptr, nullptr, N_TOK, EMB, FFN);

    // ---- phase 7: ff2 = ff1 @ W2 + b2 (BN=64 path, validated) ----
    gemm_mfma<2, 2, false, true, 0, false><<<dim3(EMB / 64, N_TOK / 64), blk, 0, stream>>>(
        ff1, W2T, b2, tmp2, nullptr, nullptr, nullptr, N_TOK, FFN, EMB);

    // ---- phase 8: out = LN(h1 + ff2) ----
    ln_kernel<false><<<dim3(N_TOK), blk, 0, stream>>>(h1, tmp2, g2, beta2, out, nullptr);
}